// Round 4
// baseline (297.892 us; speedup 1.0000x reference)
//
#include <hip/hip_runtime.h>

// ---------------- problem constants ----------------
#define LSEQ   16384        // H*W
#define NBATCH 4
#define BLROWS 65536        // B * L
#define DM     256          // d_model
#define DI     512          // d_inner
#define DXZ    1024         // 2 * d_inner

// GEMM tile
#define BM 128
#define BN 128
#define BK 64

typedef __attribute__((ext_vector_type(8))) short s16x8;
typedef __attribute__((ext_vector_type(4))) short s16x4;
typedef __attribute__((ext_vector_type(4))) float f32x4;

__device__ __forceinline__ float bf2f(unsigned short h) {
  union { unsigned u; float f; } c; c.u = ((unsigned)h) << 16; return c.f;
}
__device__ __forceinline__ unsigned short f2bf(float f) {
  union { float f; unsigned u; } c; c.f = f;
  unsigned u = c.u;
  return (unsigned short)((u + 0x7fffu + ((u >> 16) & 1u)) >> 16);
}

// ---------------- fp32 -> bf16 convert ----------------
__global__ __launch_bounds__(256)
void cvt_f32_bf16(const float* __restrict__ src, unsigned short* __restrict__ dst, int n4) {
  for (int i = blockIdx.x * blockDim.x + threadIdx.x; i < n4; i += gridDim.x * blockDim.x) {
    const float4 v = reinterpret_cast<const float4*>(src)[i];
    s16x4 o;
    o[0] = (short)f2bf(v.x);
    o[1] = (short)f2bf(v.y);
    o[2] = (short)f2bf(v.z);
    o[3] = (short)f2bf(v.w);
    reinterpret_cast<s16x4*>(dst)[i] = o;
  }
}

// ---------------- async global->LDS (16B per lane) ----------------
__device__ __forceinline__ void gload16(const void* g, void* l) {
  __builtin_amdgcn_global_load_lds((__attribute__((address_space(1))) void*)(g),
                                   (__attribute__((address_space(3))) void*)(l),
                                   16, 0, 0);
}

// ---------------- bf16 GEMM: C[M,N] = A[M,K] @ B[N,K]^T ----------------
// OUT_BF16=1 -> C is bf16 (ushort), else fp32.
template<int OUT_BF16>
__global__ __launch_bounds__(256, 2)
void gemm_bt(const unsigned short* __restrict__ A,
             const unsigned short* __restrict__ B,
             void* __restrict__ Cv,
             int M, int N, int K) {
  __shared__ unsigned short lds[2][BM * BK + BN * BK];   // 2 x 32KB

  const int tid  = threadIdx.x;
  const int lane = tid & 63;
  const int wv   = tid >> 6;        // wave 0..3
  const int wr   = wv >> 1;         // wave row 0..1  (64-row quadrant)
  const int wc   = wv & 1;          // wave col 0..1  (64-col quadrant)
  const int m0   = blockIdx.y * BM;
  const int n0   = blockIdx.x * BN;

  // staging decomposition: thread t loads 8 bf16 (16B); row = t/8 (+i*32), col = (t&7)*8
  const int srow = tid >> 3;            // 0..31
  const int scol = (tid & 7) * 8;       // 0..56

  const int kSteps = K / BK;

  f32x4 acc[4][4];
#pragma unroll
  for (int i = 0; i < 4; ++i)
#pragma unroll
    for (int j = 0; j < 4; ++j)
#pragma unroll
      for (int r = 0; r < 4; ++r) acc[i][j][r] = 0.f;

  auto stage = [&](int ks, int buf) {
    const unsigned short* Ag = A + (size_t)(m0 + srow) * K + ks * BK + scol;
    const unsigned short* Bg = B + (size_t)(n0 + srow) * K + ks * BK + scol;
    unsigned short* lA = &lds[buf][0]       + tid * 8;
    unsigned short* lB = &lds[buf][BM * BK] + tid * 8;
#pragma unroll
    for (int i = 0; i < 4; ++i) {
      gload16(Ag + (size_t)(i * 32) * K, lA + i * 2048);
      gload16(Bg + (size_t)(i * 32) * K, lB + i * 2048);
    }
  };

  stage(0, 0);

  for (int ks = 0; ks < kSteps; ++ks) {
    const int cur = ks & 1;
    __syncthreads();                       // drains vmcnt: staged buf `cur` ready
    if (ks + 1 < kSteps) stage(ks + 1, cur ^ 1);

    const unsigned short* lA = &lds[cur][0];
    const unsigned short* lB = &lds[cur][BM * BK];
    const int lrow = lane & 15;
#pragma unroll
    for (int kk = 0; kk < BK; kk += 32) {
      const int lk = kk + ((lane >> 4) << 3);
      s16x8 af[4], bf[4];
#pragma unroll
      for (int i = 0; i < 4; ++i)
        af[i] = *(const s16x8*)(lA + (wr * 64 + i * 16 + lrow) * BK + lk);
#pragma unroll
      for (int j = 0; j < 4; ++j)
        bf[j] = *(const s16x8*)(lB + (wc * 64 + j * 16 + lrow) * BK + lk);
#pragma unroll
      for (int i = 0; i < 4; ++i)
#pragma unroll
        for (int j = 0; j < 4; ++j)
          acc[i][j] = __builtin_amdgcn_mfma_f32_16x16x32_bf16(af[i], bf[j], acc[i][j], 0, 0, 0);
    }
  }

  // epilogue: C/D frag layout col = lane&15, row = (lane>>4)*4 + r
  const int r0 = (lane >> 4) * 4;
  const int c0 = lane & 15;
  if (OUT_BF16) {
    unsigned short* C = (unsigned short*)Cv;
#pragma unroll
    for (int i = 0; i < 4; ++i)
#pragma unroll
      for (int j = 0; j < 4; ++j) {
        const int rr = m0 + wr * 64 + i * 16 + r0;
        const int cc = n0 + wc * 64 + j * 16 + c0;
#pragma unroll
        for (int r = 0; r < 4; ++r)
          C[(size_t)(rr + r) * N + cc] = f2bf(acc[i][j][r]);
      }
  } else {
    float* C = (float*)Cv;
#pragma unroll
    for (int i = 0; i < 4; ++i)
#pragma unroll
      for (int j = 0; j < 4; ++j) {
        const int rr = m0 + wr * 64 + i * 16 + r0;
        const int cc = n0 + wc * 64 + j * 16 + c0;
#pragma unroll
        for (int r = 0; r < 4; ++r)
          C[(size_t)(rr + r) * N + cc] = acc[i][j][r];
      }
  }
}

// ---------------- depthwise causal conv (K=4) + SiLU + gate ----------------
// y[row, d] = 4 * silu(sum_k cw[d][k]*xb[row-3+k, d] + cb[d]) * silu(z[row, d])
// xz: [BLROWS, 1024] bf16 (x-half cols 0..511, z-half 512..1023); y: [BLROWS, 512] bf16
__global__ __launch_bounds__(256)
void conv_gate(const unsigned short* __restrict__ xz,
               const float* __restrict__ cw,    // [512][4]
               const float* __restrict__ cb,    // [512]
               unsigned short* __restrict__ y) {
  const int tid      = threadIdx.x;
  const int rowLocal = tid >> 6;                       // 0..3
  const int row      = blockIdx.x * 4 + rowLocal;      // 0..65535
  const int l        = row & (LSEQ - 1);
  const int d0       = (tid & 63) * 8;                 // channel base 0..504
  const size_t base  = (size_t)row * DXZ;

  s16x8 t[4];
#pragma unroll
  for (int k = 0; k < 4; ++k) {
    const int lp = l - 3 + k;
    if (lp >= 0) {
      t[k] = *(const s16x8*)(xz + base + (long)(k - 3) * (long)DXZ + d0);
    } else {
#pragma unroll
      for (int j = 0; j < 8; ++j) t[k][j] = 0;
    }
  }
  const s16x8 zv = *(const s16x8*)(xz + base + DI + d0);

  s16x8 o;
#pragma unroll
  for (int j = 0; j < 8; ++j) {
    const float4 wj = *(const float4*)(cw + (size_t)(d0 + j) * 4);
    float a = cb[d0 + j];
    a += wj.x * bf2f((unsigned short)t[0][j]);
    a += wj.y * bf2f((unsigned short)t[1][j]);
    a += wj.z * bf2f((unsigned short)t[2][j]);
    a += wj.w * bf2f((unsigned short)t[3][j]);
    const float su = a / (1.f + __expf(-a));
    const float zf = bf2f((unsigned short)zv[j]);
    const float sz = zf / (1.f + __expf(-zf));
    o[j] = (short)f2bf(4.f * su * sz);
  }
  *(s16x8*)(y + (size_t)row * DI + d0) = o;
}

// ---------------- launch ----------------
extern "C" void kernel_launch(void* const* d_in, const int* in_sizes, int n_in,
                              void* d_out, int out_size, void* d_ws, size_t ws_size,
                              hipStream_t stream) {
  const float* x      = (const float*)d_in[0];
  const float* W_in   = (const float*)d_in[1];
  const float* conv_w = (const float*)d_in[2];
  const float* conv_b = (const float*)d_in[3];
  const float* W_out  = (const float*)d_in[4];

  char* ws = (char*)d_ws;
  // region0 (0..64MB): x_bf16 during GEMM1, then reused as y_bf16 after conv
  unsigned short* x_bf   = (unsigned short*)(ws);
  unsigned short* y_bf   = (unsigned short*)(ws);
  unsigned short* xz_bf  = (unsigned short*)(ws + 67108864ull);
  unsigned short* win_bf = (unsigned short*)(ws + 201326592ull);
  unsigned short* wout_bf= (unsigned short*)(ws + 201850880ull);

  // 1) convert inputs to bf16
  cvt_f32_bf16<<<2048, 256, 0, stream>>>(x,      x_bf,    (BLROWS * DM) / 4);
  cvt_f32_bf16<<<256,  256, 0, stream>>>(W_in,   win_bf,  (DXZ * DM) / 4);
  cvt_f32_bf16<<<128,  256, 0, stream>>>(W_out,  wout_bf, (DM * DI) / 4);

  // 2) xz = x @ W_in^T   (65536 x 1024, K=256), bf16 out
  gemm_bt<1><<<dim3(DXZ / BN, BLROWS / BM), 256, 0, stream>>>(
      x_bf, win_bf, xz_bf, BLROWS, DXZ, DM);

  // 3) conv + silu + gate -> y (65536 x 512) bf16
  conv_gate<<<BLROWS / 4, 256, 0, stream>>>(xz_bf, conv_w, conv_b, y_bf);

  // 4) out = y @ W_out^T (65536 x 256, K=512), fp32 out
  gemm_bt<0><<<dim3(DM / BN, BLROWS / BM), 256, 0, stream>>>(
      y_bf, wout_bf, d_out, BLROWS, DM, DI);
}